// Round 9
// baseline (247.678 us; speedup 1.0000x reference)
//
#include <hip/hip_runtime.h>
#include <hip/hip_bf16.h>

// Problem sizes (fixed)
#define BB   16
#define SS   32
#define TKK  128
#define NN   512
#define LPB  4096            // S*TK rows per batch

using bf16x8 = __attribute__((ext_vector_type(8))) __bf16;
using f32x4  = __attribute__((ext_vector_type(4))) float;

__device__ inline unsigned pack_bf16(float a, float b) {
  unsigned ua = __float_as_uint(a);
  unsigned ub = __float_as_uint(b);
  ua = (ua + 0x7FFFu + ((ua >> 16) & 1u)) >> 16;   // RNE
  ub = (ub + 0x7FFFu + ((ub >> 16) & 1u)) >> 16;
  return ua | (ub << 16);
}

__device__ inline float tanh_fast(float x) {
  float e = __expf(2.0f * x);
  return 1.0f - 2.0f * __builtin_amdgcn_rcpf(e + 1.0f);
}

__device__ inline bf16x8 cvt8(f32x4 lo, f32x4 hi) {
  bf16x8 r;
  r[0] = (__bf16)lo[0]; r[1] = (__bf16)lo[1]; r[2] = (__bf16)lo[2]; r[3] = (__bf16)lo[3];
  r[4] = (__bf16)hi[0]; r[5] = (__bf16)hi[1]; r[6] = (__bf16)hi[2]; r[7] = (__bf16)hi[3];
  return r;
}

// ---------------------------------------------------------------------------
// k-permuted fragment convention (consistent across A and B, HW-validated R8):
// element e of lane-group lh holds source k = ks*32 + lh*8 + e.
// => A-frag = 32 contiguous bytes of the fp32 h row (two 16B granules).
// Wpack layout: frag g = ks*32 + mt; Wpack[g*64 + lane] = 16B bf16 frag chunk.
// ---------------------------------------------------------------------------

// ---------------------------------------------------------------------------
// prep: blocks [0,64): Wpack (direct gather, k-contiguous source);
//       blocks [64,80): dec_fea = s_t_hat @ W_d^T + b_d.
// ---------------------------------------------------------------------------
__global__ __launch_bounds__(512)
void prep_kernel(const float* __restrict__ W_h, uint4* __restrict__ Wpack,
                 const float* __restrict__ s_t_hat,
                 const float* __restrict__ W_d,
                 const float* __restrict__ b_d,
                 float* __restrict__ decfea) {
  int tid = threadIdx.x;
  if (blockIdx.x < 64) {
    int f    = blockIdx.x * 512 + tid;         // 32768 frag-chunks
    int lane = f & 63;
    int mt   = (f >> 6) & 31;
    int ks   = f >> 11;
    int m    = mt * 16 + (lane & 15);
    int lh   = lane >> 4;
    const float4* wp = reinterpret_cast<const float4*>(W_h);
    float4 a = wp[m * 128 + ks * 8 + lh * 2];
    float4 b = wp[m * 128 + ks * 8 + lh * 2 + 1];
    uint4 o;
    o.x = pack_bf16(a.x, a.y); o.y = pack_bf16(a.z, a.w);
    o.z = pack_bf16(b.x, b.y); o.w = pack_bf16(b.z, b.w);
    Wpack[f] = o;
  } else {
    int idx = (blockIdx.x - 64) * 512 + tid;   // 8192 total
    int b = idx >> 9, m = idx & 511;
    const float4* sp = reinterpret_cast<const float4*>(s_t_hat + b * NN);
    const float4* wp = reinterpret_cast<const float4*>(W_d + m * NN);
    float acc = 0.f;
    #pragma unroll 8
    for (int i = 0; i < NN / 4; ++i) {
      float4 a = sp[i], w = wp[i];
      acc += a.x * w.x + a.y * w.y + a.z * w.z + a.w * w.w;
    }
    decfea[idx] = acc + b_d[m];
  }
}

// ---------------------------------------------------------------------------
// Direct-A score kernel: 1024 blocks x 256 threads (4 waves). Wave w owns
// rows [rb*64 + w*16, +16) x ALL 512 m-cols. A-frags load global->VGPR
// directly (dense 128B-line pattern per ks), B-frags stream from L2-hot
// Wpack with an 8-deep rolling window (slot = mt&7, ks-independent).
// No operand LDS, no hot-path barrier, no cross-wave reduce.
// acc = 32 x f32x4 = 128 VGPRs; total ~195 regs under (256,2) cap.
// ---------------------------------------------------------------------------
__global__ __launch_bounds__(256, 2)
void score_kernel(const float* __restrict__ h,
                  const float* __restrict__ coverage,
                  const float* __restrict__ beta,
                  const float* __restrict__ W_c,
                  const float* __restrict__ v,
                  const uint4* __restrict__ Wpack,
                  const float* __restrict__ decfea,
                  float* __restrict__ weighted) {
  __shared__ float ep[3][NN];           // decfea, W_c, v  (6 KiB)
  int tid  = threadIdx.x;
  int lane = tid & 63;
  int w    = tid >> 6;                  // wave 0..3
  int lr   = lane & 15;                 // A row-in-tile / C col
  int lh   = lane >> 4;                 // k-group / C row-group
  int rb   = blockIdx.x;                // 1024 blocks x 64 rows
  int bidx = rb >> 6;                   // batch

  // stage epilogue scalars to LDS (one barrier, before the hot loop)
  for (int i = tid; i < NN; i += 256) {
    ep[0][i] = decfea[bidx * NN + i];
    ep[1][i] = W_c[i];
    ep[2][i] = v[i];
  }
  __syncthreads();

  int row = rb * 64 + w * 16 + lr;      // this lane's h row
  const f32x4* hrow = reinterpret_cast<const f32x4*>(h + (size_t)row * NN) + lh * 2;
  const bf16x8* Bv  = reinterpret_cast<const bf16x8*>(Wpack) + lane;

  // A pipeline: raw fp32 for ks (c) and ks+1 (n)
  f32x4 c0 = hrow[0], c1 = hrow[1];
  f32x4 n0 = hrow[8], n1 = hrow[9];

  // B rolling window: frags g = 0..7  (g = ks*32 + mt)
  bf16x8 bw[8];
  #pragma unroll
  for (int g = 0; g < 8; ++g) bw[g] = Bv[g * 64];

  f32x4 acc[32];
  const f32x4 zz = {0.f, 0.f, 0.f, 0.f};
  #pragma unroll
  for (int mt = 0; mt < 32; ++mt) acc[mt] = zz;

  for (int ks = 0; ks < 16; ++ks) {
    bf16x8 a = cvt8(c0, c1);
    c0 = n0; c1 = n1;
    int ka = (ks + 2) & 15;             // tail wraps to valid memory
    n0 = hrow[ka * 8];
    n1 = hrow[ka * 8 + 1];
    #pragma unroll
    for (int mt = 0; mt < 32; ++mt) {
      bf16x8 bcur = bw[mt & 7];
      int g = (ks * 32 + mt + 8) & 511; // prefetch 8 frags ahead (tail wraps)
      bw[mt & 7] = Bv[g * 64];
      acc[mt] = __builtin_amdgcn_mfma_f32_16x16x32_bf16(a, bcur, acc[mt], 0, 0, 0);
    }
  }

  // ---- epilogue: + dec_fea + cov*W_c, tanh, v-weighted sum over m ----
  float cvl[4];
  #pragma unroll
  for (int r = 0; r < 4; ++r)
    cvl[r] = coverage[rb * 64 + w * 16 + lh * 4 + r];

  float sc[4] = {0.f, 0.f, 0.f, 0.f};
  #pragma unroll
  for (int mt = 0; mt < 32; ++mt) {
    int m = mt * 16 + lr;
    float dvm = ep[0][m], wcm = ep[1][m], vvm = ep[2][m];
    #pragma unroll
    for (int r = 0; r < 4; ++r) {
      float x = acc[mt][r] + dvm + cvl[r] * wcm;
      sc[r] += vvm * tanh_fast(x);
    }
  }
  #pragma unroll
  for (int r = 0; r < 4; ++r) {
    float s = sc[r];
    s += __shfl_xor(s, 1);
    s += __shfl_xor(s, 2);
    s += __shfl_xor(s, 4);
    s += __shfl_xor(s, 8);
    sc[r] = s;
  }
  if (lr == 0) {
    #pragma unroll
    for (int r = 0; r < 4; ++r) {
      int gl = rb * 64 + w * 16 + lh * 4 + r;
      int lb = gl & (LPB - 1);
      int s  = lb >> 7;                 // TK = 128
      weighted[bidx * LPB + lb] = beta[bidx * SS + s] * sc[r];
    }
  }
}

// ---------------------------------------------------------------------------
// Softmax over 4096 per batch, mask, renormalize; write attn_dist + coverage_new.
// Also zeroes c_t for the following atomic-accumulate kernel.
// ---------------------------------------------------------------------------
__global__ void softmax_kernel(const float* __restrict__ coverage,
                               const float* __restrict__ mask,
                               float* __restrict__ out) {
  int b = blockIdx.x;
  int t = threadIdx.x;
  float* ct   = out;                     // [0, 8192)
  float* attn = out + 8192;              // weighted in, attn_dist out
  float* covn = out + 8192 + 65536;      // coverage_new

  ct[b * NN + t] = 0.f;
  ct[b * NN + 256 + t] = 0.f;

  float wv[16];
  float mx = -1e30f;
  #pragma unroll
  for (int i = 0; i < 16; ++i) {
    wv[i] = attn[b * LPB + i * 256 + t];
    mx = fmaxf(mx, wv[i]);
  }
  __shared__ float redm[4], reds[4];
  mx = fmaxf(mx, __shfl_xor(mx, 1));
  mx = fmaxf(mx, __shfl_xor(mx, 2));
  mx = fmaxf(mx, __shfl_xor(mx, 4));
  mx = fmaxf(mx, __shfl_xor(mx, 8));
  mx = fmaxf(mx, __shfl_xor(mx, 16));
  mx = fmaxf(mx, __shfl_xor(mx, 32));
  if ((t & 63) == 0) redm[t >> 6] = mx;
  __syncthreads();
  mx = fmaxf(fmaxf(redm[0], redm[1]), fmaxf(redm[2], redm[3]));

  float e[16];
  float sum = 0.f;
  #pragma unroll
  for (int i = 0; i < 16; ++i) {
    e[i] = __expf(wv[i] - mx) * mask[b * LPB + i * 256 + t];
    sum += e[i];
  }
  sum += __shfl_xor(sum, 1);
  sum += __shfl_xor(sum, 2);
  sum += __shfl_xor(sum, 4);
  sum += __shfl_xor(sum, 8);
  sum += __shfl_xor(sum, 16);
  sum += __shfl_xor(sum, 32);
  if ((t & 63) == 0) reds[t >> 6] = sum;
  __syncthreads();
  sum = reds[0] + reds[1] + reds[2] + reds[3];
  float inv = 1.0f / sum;
  #pragma unroll
  for (int i = 0; i < 16; ++i) {
    int l = i * 256 + t;
    float a = e[i] * inv;
    attn[b * LPB + l] = a;
    covn[b * LPB + l] = coverage[b * LPB + l] + a;
  }
}

// ---------------------------------------------------------------------------
// c_t[b][n] = sum_l attn[b][l] * h[b][l][n]  (memory-bound, atomic partials)
// R3-proven version: float2 loads, one atomic per distinct address.
// ---------------------------------------------------------------------------
__global__ void ct_kernel(const float* __restrict__ h, float* __restrict__ out) {
  int blk   = blockIdx.x;                // 1024
  int b     = blk >> 6;
  int chunk = blk & 63;
  int t     = threadIdx.x;
  const float* attn = out + 8192 + b * LPB + chunk * 64;
  __shared__ float as_[64];
  if (t < 64) as_[t] = attn[t];
  __syncthreads();
  const float* hp = h + (size_t)(b * LPB + chunk * 64) * NN;
  float a0 = 0.f, a1 = 0.f;
  #pragma unroll 4
  for (int r = 0; r < 64; ++r) {
    float2 hv = *reinterpret_cast<const float2*>(hp + r * NN + t * 2);
    float av = as_[r];
    a0 += av * hv.x;
    a1 += av * hv.y;
  }
  atomicAdd(&out[b * NN + t * 2],     a0);
  atomicAdd(&out[b * NN + t * 2 + 1], a1);
}

extern "C" void kernel_launch(void* const* d_in, const int* in_sizes, int n_in,
                              void* d_out, int out_size, void* d_ws, size_t ws_size,
                              hipStream_t stream) {
  const float* s_t_hat  = (const float*)d_in[0];
  const float* h        = (const float*)d_in[1];
  const float* coverage = (const float*)d_in[2];
  const float* mask     = (const float*)d_in[3];
  const float* beta     = (const float*)d_in[4];
  const float* W_h      = (const float*)d_in[5];
  const float* W_c      = (const float*)d_in[6];
  const float* W_d      = (const float*)d_in[7];
  const float* b_d      = (const float*)d_in[8];
  const float* v        = (const float*)d_in[9];
  float* out = (float*)d_out;

  uint4* Wpack    = (uint4*)d_ws;               // 512 KiB
  float* decfea   = out + 8192 + 65536;         // staged in coverage_new region
  float* weighted = out + 8192;                 // staged in attn_dist region

  prep_kernel <<<80, 512, 0, stream>>>(W_h, Wpack, s_t_hat, W_d, b_d, decfea);
  score_kernel<<<1024, 256, 0, stream>>>(h, coverage, beta, W_c, v,
                                         Wpack, decfea, weighted);
  softmax_kernel<<<16, 256, 0, stream>>>(coverage, mask, out);
  ct_kernel<<<1024, 256, 0, stream>>>(h, out);
}

// Round 10
// 230.123 us; speedup vs baseline: 1.0763x; 1.0763x over previous
//
#include <hip/hip_runtime.h>
#include <hip/hip_bf16.h>

// Problem sizes (fixed)
#define BB   16
#define SS   32
#define TKK  128
#define NN   512
#define LPB  4096            // S*TK rows per batch

using bf16x8 = __attribute__((ext_vector_type(8))) __bf16;
using f32x4  = __attribute__((ext_vector_type(4))) float;

__device__ inline unsigned pack_bf16(float a, float b) {
  unsigned ua = __float_as_uint(a);
  unsigned ub = __float_as_uint(b);
  ua = (ua + 0x7FFFu + ((ua >> 16) & 1u)) >> 16;   // RNE
  ub = (ub + 0x7FFFu + ((ub >> 16) & 1u)) >> 16;
  return ua | (ub << 16);
}

__device__ inline float tanh_fast(float x) {
  float e = __expf(2.0f * x);
  return 1.0f - 2.0f * __builtin_amdgcn_rcpf(e + 1.0f);
}

// ---------------------------------------------------------------------------
// k-permuted fragment convention (consistent across A and B, HW-validated R8/R9):
// element e of lane-group lh (= lane>>4) holds source k = ks*32 + lh*8 + e.
// => A-frag = 16 contiguous bf16 of the row; B-frag chunk = 16B from Wpack.
// Wpack index f = ks*2048 + mt*64 + lane.
// LDS A layout: row-major bf16 [64][512], 16B chunks swizzled:
//   stored_chunk = c64 ^ (row&7) ^ (c64>>3), c64 = k/8 in [0,64).
// ---------------------------------------------------------------------------

// ---------------------------------------------------------------------------
// prep: blocks [0,64): Wpack (direct gather, k-contiguous source);
//       blocks [64,80): dec_fea = s_t_hat @ W_d^T + b_d.     (R9-proven)
// ---------------------------------------------------------------------------
__global__ __launch_bounds__(512)
void prep_kernel(const float* __restrict__ W_h, uint4* __restrict__ Wpack,
                 const float* __restrict__ s_t_hat,
                 const float* __restrict__ W_d,
                 const float* __restrict__ b_d,
                 float* __restrict__ decfea) {
  int tid = threadIdx.x;
  if (blockIdx.x < 64) {
    int f    = blockIdx.x * 512 + tid;         // 32768 frag-chunks
    int lane = f & 63;
    int mt   = (f >> 6) & 31;
    int ks   = f >> 11;
    int m    = mt * 16 + (lane & 15);
    int lh   = lane >> 4;
    const float4* wp = reinterpret_cast<const float4*>(W_h);
    float4 a = wp[m * 128 + ks * 8 + lh * 2];
    float4 b = wp[m * 128 + ks * 8 + lh * 2 + 1];
    uint4 o;
    o.x = pack_bf16(a.x, a.y); o.y = pack_bf16(a.z, a.w);
    o.z = pack_bf16(b.x, b.y); o.w = pack_bf16(b.z, b.w);
    Wpack[f] = o;
  } else {
    int idx = (blockIdx.x - 64) * 512 + tid;   // 8192 total
    int b = idx >> 9, m = idx & 511;
    const float4* sp = reinterpret_cast<const float4*>(s_t_hat + b * NN);
    const float4* wp = reinterpret_cast<const float4*>(W_d + m * NN);
    float acc = 0.f;
    #pragma unroll 8
    for (int i = 0; i < NN / 4; ++i) {
      float4 a = sp[i], w = wp[i];
      acc += a.x * w.x + a.y * w.y + a.z * w.z + a.w * w.w;
    }
    decfea[idx] = acc + b_d[m];
  }
}

// ---------------------------------------------------------------------------
// Score kernel: 512 blocks x 512 threads (8 waves), 2 tiles (64 rows each)
// per block. T14 async-STAGE: tile t+1's global loads issued BEFORE tile t's
// MFMA loop (held in 16 float4 regs), converted+ds_written after the
// reads-done barrier. Waves split m 4-ways (wm) x rows 2-ways (wr):
// acc = 8q x 2j x f32x4 = 64. B depth-1 rolling window from L2-hot Wpack.
// ---------------------------------------------------------------------------
__global__ __launch_bounds__(512, 2)
void score_kernel(const float* __restrict__ h,
                  const float* __restrict__ coverage,
                  const float* __restrict__ beta,
                  const float* __restrict__ W_c,
                  const float* __restrict__ v,
                  const uint4* __restrict__ Wpack,
                  const float* __restrict__ decfea,
                  float* __restrict__ weighted) {
  __shared__ __align__(16) uint4 Alds4[4096];     // 64 KiB bf16 A tile
  __shared__ float scorebuf[4][64];               // 1 KiB
  int tid  = threadIdx.x;
  int lane = tid & 63;
  int w    = tid >> 6;                  // wave 0..7
  int wm   = w & 3;                     // m-split
  int wr   = w >> 2;                    // row-split
  int lr   = lane & 15;                 // A row-in-tile / C col
  int lh   = lane >> 4;                 // k-group / C row-group
  int rhi  = lh << 2;                   // C/D row base
  int srow = tid >> 3;                  // staging row
  int seg  = tid & 7;                   // staging k-segment (64 floats)
  int tile0 = blockIdx.x * 2;
  int bidx  = tile0 >> 6;               // batch (both tiles same batch)

  const bf16x8* Alds8 = reinterpret_cast<const bf16x8*>(Alds4);
  const bf16x8* Bq    = reinterpret_cast<const bf16x8*>(Wpack) + lane;

  // hoisted per-batch epilogue operands
  float dv[8], wc[8], vv[8];
  #pragma unroll
  for (int q = 0; q < 8; ++q) {
    int m = (wm * 8 + q) * 16 + lr;
    dv[q] = decfea[bidx * NN + m];
    wc[q] = W_c[m];
    vv[q] = v[m];
  }

  float4 sg[16];

  // ---- prologue: stage tile0 ----
  {
    const float4* p = reinterpret_cast<const float4*>(h + (size_t)tile0 * 64 * NN + srow * NN + seg * 64);
    #pragma unroll
    for (int i = 0; i < 16; ++i) sg[i] = p[i];
    #pragma unroll
    for (int c = 0; c < 8; ++c) {
      float4 a = sg[2 * c], b = sg[2 * c + 1];
      uint4 o;
      o.x = pack_bf16(a.x, a.y); o.y = pack_bf16(a.z, a.w);
      o.z = pack_bf16(b.x, b.y); o.w = pack_bf16(b.z, b.w);
      int c64 = seg * 8 + c;
      Alds4[srow * 64 + (c64 ^ (srow & 7) ^ seg)] = o;
    }
  }
  __syncthreads();

  #pragma unroll
  for (int t = 0; t < 2; ++t) {
    int tile = tile0 + t;

    // issue next tile's loads early (latency hides under MFMA loop)
    if (t == 0) {
      const float4* p = reinterpret_cast<const float4*>(h + (size_t)(tile0 + 1) * 64 * NN + srow * NN + seg * 64);
      #pragma unroll
      for (int i = 0; i < 16; ++i) sg[i] = p[i];
    }

    // ---- MFMA loop: B depth-1 rolling, A from swizzled LDS ----
    f32x4 acc[8][2];
    const f32x4 zz = {0.f, 0.f, 0.f, 0.f};
    #pragma unroll
    for (int q = 0; q < 8; ++q) { acc[q][0] = zz; acc[q][1] = zz; }

    bf16x8 bb[8];
    #pragma unroll
    for (int q = 0; q < 8; ++q) bb[q] = Bq[(0 * 32 + wm * 8 + q) * 64];

    int arow0 = (2 * wr + 0) * 16 + lr;
    int arow1 = (2 * wr + 1) * 16 + lr;

    #pragma unroll
    for (int ks = 0; ks < 16; ++ks) {
      int c64  = ks * 4 + lh;
      int sc64 = c64 ^ (lr & 7) ^ (ks >> 1);     // (row&7)==(lr&7)
      bf16x8 af0 = Alds8[arow0 * 64 + sc64];
      bf16x8 af1 = Alds8[arow1 * 64 + sc64];
      bf16x8 bn[8];
      if (ks < 15) {
        #pragma unroll
        for (int q = 0; q < 8; ++q) bn[q] = Bq[((ks + 1) * 32 + wm * 8 + q) * 64];
      }
      #pragma unroll
      for (int q = 0; q < 8; ++q) {
        acc[q][0] = __builtin_amdgcn_mfma_f32_16x16x32_bf16(af0, bb[q], acc[q][0], 0, 0, 0);
        acc[q][1] = __builtin_amdgcn_mfma_f32_16x16x32_bf16(af1, bb[q], acc[q][1], 0, 0, 0);
      }
      if (ks < 15) {
        #pragma unroll
        for (int q = 0; q < 8; ++q) bb[q] = bn[q];
      }
    }

    __syncthreads();                   // all LDS A-reads of tile t done

    // ---- write next tile into LDS (loads long in flight) ----
    if (t == 0) {
      #pragma unroll
      for (int c = 0; c < 8; ++c) {
        float4 a = sg[2 * c], b = sg[2 * c + 1];
        uint4 o;
        o.x = pack_bf16(a.x, a.y); o.y = pack_bf16(a.z, a.w);
        o.z = pack_bf16(b.x, b.y); o.w = pack_bf16(b.z, b.w);
        int c64 = seg * 8 + c;
        Alds4[srow * 64 + (c64 ^ (srow & 7) ^ seg)] = o;
      }
    }

    // ---- epilogue: + dec_fea + cov*W_c, tanh, v-weighted reduce over m ----
    float cvl[2][4];
    #pragma unroll
    for (int j = 0; j < 2; ++j)
      #pragma unroll
      for (int r = 0; r < 4; ++r)
        cvl[j][r] = coverage[tile * 64 + (2 * wr + j) * 16 + rhi + r];

    float sc[2][4] = {};
    #pragma unroll
    for (int q = 0; q < 8; ++q)
      #pragma unroll
      for (int j = 0; j < 2; ++j)
        #pragma unroll
        for (int r = 0; r < 4; ++r) {
          float x = acc[q][j][r] + dv[q] + cvl[j][r] * wc[q];
          sc[j][r] += vv[q] * tanh_fast(x);
        }
    #pragma unroll
    for (int j = 0; j < 2; ++j)
      #pragma unroll
      for (int r = 0; r < 4; ++r) {
        float s = sc[j][r];
        s += __shfl_xor(s, 1);
        s += __shfl_xor(s, 2);
        s += __shfl_xor(s, 4);
        s += __shfl_xor(s, 8);
        sc[j][r] = s;
      }
    if (lr == 0) {
      #pragma unroll
      for (int j = 0; j < 2; ++j)
        #pragma unroll
        for (int r = 0; r < 4; ++r)
          scorebuf[wm][(2 * wr + j) * 16 + rhi + r] = sc[j][r];
    }
    __syncthreads();                   // scorebuf ready + ds_writes drained
    if (tid < 64) {
      float total = scorebuf[0][tid] + scorebuf[1][tid] + scorebuf[2][tid] + scorebuf[3][tid];
      int gl = tile * 64 + tid;
      int lb = gl & (LPB - 1);
      int s  = lb >> 7;                // TK = 128
      weighted[bidx * LPB + lb] = beta[bidx * SS + s] * total;
    }
    if (t == 0) __syncthreads();       // weighted reads done before next epilogue writes
  }
}

// ---------------------------------------------------------------------------
// Softmax over 4096 per batch, mask, renormalize; write attn_dist + coverage_new.
// Also zeroes c_t for the following atomic-accumulate kernel.
// ---------------------------------------------------------------------------
__global__ void softmax_kernel(const float* __restrict__ coverage,
                               const float* __restrict__ mask,
                               float* __restrict__ out) {
  int b = blockIdx.x;
  int t = threadIdx.x;
  float* ct   = out;                     // [0, 8192)
  float* attn = out + 8192;              // weighted in, attn_dist out
  float* covn = out + 8192 + 65536;      // coverage_new

  ct[b * NN + t] = 0.f;
  ct[b * NN + 256 + t] = 0.f;

  float wv[16];
  float mx = -1e30f;
  #pragma unroll
  for (int i = 0; i < 16; ++i) {
    wv[i] = attn[b * LPB + i * 256 + t];
    mx = fmaxf(mx, wv[i]);
  }
  __shared__ float redm[4], reds[4];
  mx = fmaxf(mx, __shfl_xor(mx, 1));
  mx = fmaxf(mx, __shfl_xor(mx, 2));
  mx = fmaxf(mx, __shfl_xor(mx, 4));
  mx = fmaxf(mx, __shfl_xor(mx, 8));
  mx = fmaxf(mx, __shfl_xor(mx, 16));
  mx = fmaxf(mx, __shfl_xor(mx, 32));
  if ((t & 63) == 0) redm[t >> 6] = mx;
  __syncthreads();
  mx = fmaxf(fmaxf(redm[0], redm[1]), fmaxf(redm[2], redm[3]));

  float e[16];
  float sum = 0.f;
  #pragma unroll
  for (int i = 0; i < 16; ++i) {
    e[i] = __expf(wv[i] - mx) * mask[b * LPB + i * 256 + t];
    sum += e[i];
  }
  sum += __shfl_xor(sum, 1);
  sum += __shfl_xor(sum, 2);
  sum += __shfl_xor(sum, 4);
  sum += __shfl_xor(sum, 8);
  sum += __shfl_xor(sum, 16);
  sum += __shfl_xor(sum, 32);
  if ((t & 63) == 0) reds[t >> 6] = sum;
  __syncthreads();
  sum = reds[0] + reds[1] + reds[2] + reds[3];
  float inv = 1.0f / sum;
  #pragma unroll
  for (int i = 0; i < 16; ++i) {
    int l = i * 256 + t;
    float a = e[i] * inv;
    attn[b * LPB + l] = a;
    covn[b * LPB + l] = coverage[b * LPB + l] + a;
  }
}

// ---------------------------------------------------------------------------
// c_t[b][n] = sum_l attn[b][l] * h[b][l][n]  (memory-bound, atomic partials)
// ---------------------------------------------------------------------------
__global__ void ct_kernel(const float* __restrict__ h, float* __restrict__ out) {
  int blk   = blockIdx.x;                // 1024
  int b     = blk >> 6;
  int chunk = blk & 63;
  int t     = threadIdx.x;
  const float* attn = out + 8192 + b * LPB + chunk * 64;
  __shared__ float as_[64];
  if (t < 64) as_[t] = attn[t];
  __syncthreads();
  const float* hp = h + (size_t)(b * LPB + chunk * 64) * NN;
  float a0 = 0.f, a1 = 0.f;
  #pragma unroll 4
  for (int r = 0; r < 64; ++r) {
    float2 hv = *reinterpret_cast<const float2*>(hp + r * NN + t * 2);
    float av = as_[r];
    a0 += av * hv.x;
    a1 += av * hv.y;
  }
  atomicAdd(&out[b * NN + t * 2],     a0);
  atomicAdd(&out[b * NN + t * 2 + 1], a1);
}

extern "C" void kernel_launch(void* const* d_in, const int* in_sizes, int n_in,
                              void* d_out, int out_size, void* d_ws, size_t ws_size,
                              hipStream_t stream) {
  const float* s_t_hat  = (const float*)d_in[0];
  const float* h        = (const float*)d_in[1];
  const float* coverage = (const float*)d_in[2];
  const float* mask     = (const float*)d_in[3];
  const float* beta     = (const float*)d_in[4];
  const float* W_h      = (const float*)d_in[5];
  const float* W_c      = (const float*)d_in[6];
  const float* W_d      = (const float*)d_in[7];
  const float* b_d      = (const float*)d_in[8];
  const float* v        = (const float*)d_in[9];
  float* out = (float*)d_out;

  uint4* Wpack    = (uint4*)d_ws;               // 512 KiB
  float* decfea   = out + 8192 + 65536;         // staged in coverage_new region
  float* weighted = out + 8192;                 // staged in attn_dist region

  prep_kernel <<<80, 512, 0, stream>>>(W_h, Wpack, s_t_hat, W_d, b_d, decfea);
  score_kernel<<<512, 512, 0, stream>>>(h, coverage, beta, W_c, v,
                                        Wpack, decfea, weighted);
  softmax_kernel<<<16, 256, 0, stream>>>(coverage, mask, out);
  ct_kernel<<<1024, 256, 0, stream>>>(h, out);
}